// Round 3
// baseline (11.636 us; speedup 1.0000x reference)
//
#include <hip/hip_runtime.h>

// DWT_1D (Haar, band length 2): Lo[m] = (x[2m]+x[2m+1])/sqrt(2),
//                               Hi[m] = (x[2m]-x[2m+1])/sqrt(2)
// x: (8,64,8192) fp32 -> Lo,Hi: (8,64,4096) fp32, concatenated in d_out.
// Matrices d_in[1]/d_in[2] are fixed Haar Toeplitz structure; unused.
//
// R3: same as R2 but with clang ext_vector_type so nontemporal builtins
// compile (HIP float4 is a class type, rejected by the builtin).
// 64B/lane: 4x 16B loads, 2+2 16B stores; 4096 waves.

#define INV_SQRT2 0.70710678118654752440f

typedef float vf4 __attribute__((ext_vector_type(4)));

__global__ __launch_bounds__(256) void dwt1d_haar_kernel(
    const vf4* __restrict__ x4,   // input as vf4; 4 consumed per thread
    vf4* __restrict__ lo4,        // d_out first half
    vf4* __restrict__ hi4,        // d_out second half
    int npair)                    // number of lo/hi vf4 PAIRS = half/8
{
    int t = blockIdx.x * blockDim.x + threadIdx.x;
    if (t >= npair) return;

    // 16 consecutive input floats -> 8 Lo + 8 Hi outputs (2 vf4 each)
    vf4 a = __builtin_nontemporal_load(&x4[4 * t + 0]);
    vf4 b = __builtin_nontemporal_load(&x4[4 * t + 1]);
    vf4 c = __builtin_nontemporal_load(&x4[4 * t + 2]);
    vf4 d = __builtin_nontemporal_load(&x4[4 * t + 3]);

    vf4 lo0, lo1, hi0, hi1;
    lo0.x = (a.x + a.y) * INV_SQRT2;  hi0.x = (a.x - a.y) * INV_SQRT2;
    lo0.y = (a.z + a.w) * INV_SQRT2;  hi0.y = (a.z - a.w) * INV_SQRT2;
    lo0.z = (b.x + b.y) * INV_SQRT2;  hi0.z = (b.x - b.y) * INV_SQRT2;
    lo0.w = (b.z + b.w) * INV_SQRT2;  hi0.w = (b.z - b.w) * INV_SQRT2;

    lo1.x = (c.x + c.y) * INV_SQRT2;  hi1.x = (c.x - c.y) * INV_SQRT2;
    lo1.y = (c.z + c.w) * INV_SQRT2;  hi1.y = (c.z - c.w) * INV_SQRT2;
    lo1.z = (d.x + d.y) * INV_SQRT2;  hi1.z = (d.x - d.y) * INV_SQRT2;
    lo1.w = (d.z + d.w) * INV_SQRT2;  hi1.w = (d.z - d.w) * INV_SQRT2;

    __builtin_nontemporal_store(lo0, &lo4[2 * t + 0]);
    __builtin_nontemporal_store(lo1, &lo4[2 * t + 1]);
    __builtin_nontemporal_store(hi0, &hi4[2 * t + 0]);
    __builtin_nontemporal_store(hi1, &hi4[2 * t + 1]);
}

extern "C" void kernel_launch(void* const* d_in, const int* in_sizes, int n_in,
                              void* d_out, int out_size, void* d_ws, size_t ws_size,
                              hipStream_t stream) {
    const float* x = (const float*)d_in[0];
    float* out = (float*)d_out;

    // out_size = 2 * half  (Lo then Hi, each 8*64*4096 floats)
    const int half  = out_size / 2;          // 2,097,152
    const int npair = half / 8;              // 262,144 threads

    vf4* lo4 = (vf4*)out;
    vf4* hi4 = (vf4*)(out + half);
    const vf4* x4 = (const vf4*)x;

    const int block = 256;
    const int grid  = (npair + block - 1) / block;  // 1024
    dwt1d_haar_kernel<<<grid, block, 0, stream>>>(x4, lo4, hi4, npair);
}

// Round 4
// 11.616 us; speedup vs baseline: 1.0017x; 1.0017x over previous
//
#include <hip/hip_runtime.h>

// DWT_1D (Haar, band length 2): Lo[m] = (x[2m]+x[2m+1])/sqrt(2),
//                               Hi[m] = (x[2m]-x[2m+1])/sqrt(2)
// x: (8,64,8192) fp32 -> Lo,Hi: (8,64,4096) fp32, concatenated in d_out.
// Matrices d_in[1]/d_in[2] are fixed Haar Toeplitz structure; unused.
//
// R4: cached (no nt) accesses — working set is L3-resident across replays.
// Perfect per-instruction coalescing: each lane handles one float4 (2 Haar
// pairs) per step -> float2 to Lo + float2 to Hi. Loads 16B/lane contiguous,
// stores 8B/lane contiguous. 2 steps/thread, 2048 blocks x 256.

#define INV_SQRT2 0.70710678118654752440f

typedef float vf4 __attribute__((ext_vector_type(4)));
typedef float vf2 __attribute__((ext_vector_type(2)));

__global__ __launch_bounds__(256) void dwt1d_haar_kernel(
    const vf4* __restrict__ x4,   // input as float4 granules (2 pairs each)
    vf2* __restrict__ lo2,        // d_out first half as float2 granules
    vf2* __restrict__ hi2,        // d_out second half as float2 granules
    int n4)                       // total input float4 granules
{
    int g = blockIdx.x * 512 + threadIdx.x;

    // step 0
    if (g < n4) {
        vf4 a = x4[g];
        vf2 lo, hi;
        lo.x = (a.x + a.y) * INV_SQRT2;
        lo.y = (a.z + a.w) * INV_SQRT2;
        hi.x = (a.x - a.y) * INV_SQRT2;
        hi.y = (a.z - a.w) * INV_SQRT2;
        lo2[g] = lo;
        hi2[g] = hi;
    }

    // step 1
    g += 256;
    if (g < n4) {
        vf4 a = x4[g];
        vf2 lo, hi;
        lo.x = (a.x + a.y) * INV_SQRT2;
        lo.y = (a.z + a.w) * INV_SQRT2;
        hi.x = (a.x - a.y) * INV_SQRT2;
        hi.y = (a.z - a.w) * INV_SQRT2;
        lo2[g] = lo;
        hi2[g] = hi;
    }
}

extern "C" void kernel_launch(void* const* d_in, const int* in_sizes, int n_in,
                              void* d_out, int out_size, void* d_ws, size_t ws_size,
                              hipStream_t stream) {
    const float* x = (const float*)d_in[0];
    float* out = (float*)d_out;

    // out_size = 2 * half  (Lo then Hi, each 8*64*4096 floats)
    const int half = out_size / 2;           // 2,097,152 floats per output
    const int n4   = half / 2;               // 1,048,576 input float4 granules

    vf2* lo2 = (vf2*)out;
    vf2* hi2 = (vf2*)(out + half);
    const vf4* x4 = (const vf4*)x;

    const int block = 256;
    const int grid  = (n4 + 512 - 1) / 512;  // 2048 blocks, 2 steps each
    dwt1d_haar_kernel<<<grid, block, 0, stream>>>(x4, lo2, hi2, n4);
}